// Round 2
// baseline (99.938 us; speedup 1.0000x reference)
//
#include <hip/hip_runtime.h>
#include <math.h>
#include <float.h>

// ChamferLoss: set1/set2 [8, 4096, 3] fp32 -> scalar
// out = sum over both directions of per-point min distances / (8*4096*4096)
//
// v3: points-in-SGPR design. v2 post-mortem showed the kernel is
// stall/overlap-bound (LDS broadcast reads were never the throughput cost;
// killing occupancy to 1 block/CU regressed). So: eliminate LDS staging
// entirely. A pre-kernel packs {x,y,z,||p||^2} float4s into d_ws; the main
// kernel scans points with a WAVE-UNIFORM index (readfirstlane'd wave id),
// letting the compiler select s_load (scalar pipe) for the point stream.
// Per wave: 2 queries/lane (128/block), 512 points, partial mins combined
// via a tiny 4KB LDS array. No staging loop, no big sync domain,
// 2 blocks/CU, 4 waves/SIMD. VALU floor ~13.7 us.

#define BATCH   8
#define NPTS    4096
#define THREADS 512
#define QB      128          // queries per block (64 lanes * QPT)
#define QPT     2            // queries per thread
#define NWAVES  8            // waves per block, each scans PPW points
#define PPW     (NPTS/NWAVES)  // 512 points per wave

__global__ __launch_bounds__(256)
void pack_pts(const float* __restrict__ set1,
              const float* __restrict__ set2,
              float4* __restrict__ pk)
{
    const int i = blockIdx.x * 256 + threadIdx.x;   // 0..65535
    const float* __restrict__ src = (i < BATCH * NPTS) ? set1 : set2;
    const int idx = i & (BATCH * NPTS - 1);
    const float x = src[3 * idx + 0];
    const float y = src[3 * idx + 1];
    const float z = src[3 * idx + 2];
    pk[i] = make_float4(x, y, z, fmaf(x, x, fmaf(y, y, z * z)));
}

__global__ __launch_bounds__(THREADS, 4)
void chamfer_main(const float4* __restrict__ pk,
                  float* __restrict__ out)
{
    __shared__ float part[NWAVES][QB];    // 4 KB

    const int blk = blockIdx.x;           // 0..511
    const int dir = blk >> 8;             // 0: set1->set2, 1: set2->set1
    const int rem = blk & 255;
    const int b   = rem >> 5;             // batch 0..7
    const int qc  = rem & 31;             // query chunk 0..31
    const int qbase = qc * QB;

    // packed set1 at pk[0..32767], packed set2 at pk[32768..65535]
    const float4* __restrict__ Qb  = pk + (dir ? BATCH * NPTS : 0) + (size_t)b * NPTS;
    const float4* __restrict__ DBb = pk + (dir ? 0 : BATCH * NPTS) + (size_t)b * NPTS;

    const int t    = threadIdx.x;
    const int lane = t & 63;
    const int w    = __builtin_amdgcn_readfirstlane(t >> 6);  // provably uniform

    // --- this thread's query coefficient sets (-2*q) ---
    float qa[QPT], qbv[QPT], qcv[QPT], dmin[QPT];
    #pragma unroll
    for (int j = 0; j < QPT; ++j) {
        const float4 q = Qb[qbase + lane + 64 * j];
        qa[j]  = -2.0f * q.x;
        qbv[j] = -2.0f * q.y;
        qcv[j] = -2.0f * q.z;
        dmin[j] = FLT_MAX;
    }

    // --- scan this wave's 512 points with a uniform index (s_load path) ---
    const float4* __restrict__ P = DBb + w * PPW;

    for (int c = 0; c < PPW; c += 8) {
        float d[QPT][8];
        #pragma unroll
        for (int k = 0; k < 8; ++k) {
            const float4 p = P[c + k];     // wave-uniform address
            #pragma unroll
            for (int j = 0; j < QPT; ++j) {
                d[j][k] = fmaf(qa[j], p.x,
                          fmaf(qbv[j], p.y,
                          fmaf(qcv[j], p.z, p.w)));
            }
        }
        #pragma unroll
        for (int j = 0; j < QPT; ++j) {
            // v_min3 tree over 8 candidates + running min
            const float m0 = fminf(fminf(d[j][0], d[j][1]), d[j][2]);
            const float m1 = fminf(fminf(d[j][3], d[j][4]), m0);
            const float m2 = fminf(fminf(d[j][5], d[j][6]), m1);
            dmin[j] = fminf(fminf(d[j][7], m2), dmin[j]);
        }
    }

    // --- write per-wave partial mins ---
    #pragma unroll
    for (int j = 0; j < QPT; ++j)
        part[w][lane + 64 * j] = dmin[j];
    __syncthreads();

    // --- combine waves, finish d = sqrt(max(q^2 + m, 0)), reduce sum ---
    float dist = 0.0f;
    if (t < QB) {
        float m = part[0][t];
        #pragma unroll
        for (int ww = 1; ww < NWAVES; ++ww)
            m = fminf(m, part[ww][t]);
        const float4 q = Qb[qbase + t];    // .w = ||q||^2
        dist = sqrtf(fmaxf(q.w + m, 0.0f));
    }

    // wave reduce (only waves 0,1 have nonzero), one atomic per wave
    #pragma unroll
    for (int off = 32; off > 0; off >>= 1)
        dist += __shfl_down(dist, off);
    if (t < QB && (t & 63) == 0)
        atomicAdd(out, dist * (1.0f / (float)((size_t)BATCH * NPTS * NPTS)));
}

extern "C" void kernel_launch(void* const* d_in, const int* in_sizes, int n_in,
                              void* d_out, int out_size, void* d_ws, size_t ws_size,
                              hipStream_t stream) {
    const float* s1 = (const float*)d_in[0];
    const float* s2 = (const float*)d_in[1];
    float* out = (float*)d_out;
    float4* pk = (float4*)d_ws;            // needs 1 MB; ws is far larger

    hipMemsetAsync(out, 0, sizeof(float), stream);  // d_out poisoned 0xAA each call
    pack_pts<<<dim3((2 * BATCH * NPTS) / 256), dim3(256), 0, stream>>>(s1, s2, pk);
    chamfer_main<<<dim3(512), dim3(THREADS), 0, stream>>>(pk, out);
}

// Round 3
// 79.101 us; speedup vs baseline: 1.2634x; 1.2634x over previous
//
#include <hip/hip_runtime.h>
#include <math.h>
#include <float.h>

// ChamferLoss: set1/set2 [8, 4096, 3] fp32 -> scalar
// out = (sum of per-point min dists, both directions) / (8*4096*4096)
//
// v4: MFMA path. d^2 = q^2 + (p^2 - 2 q.p); the (p^2 - 2 q.p) term for a
// 32x32 (point x query) tile is ONE v_mfma_f32_32x32x16_bf16 with the
// fp32->bf16 hi/lo split packed into K:
//   k0-2 : ph .  -2qh      k3-5 : pl . -2qh
//   k6-8 : ph .  -2ql      k9-11: pl . -2ql
//   k12-14: (p2a,p2b,p2c) . (1,1,1)     k15: 0
// => exactly p2~ - 2*(qh+ql).(ph+pl); d^2 error ~2e-6 (output err ~1e-9).
// Row (point) permutation of the C/D layout is irrelevant (min over rows);
// col=lane&31 (query) is the HW-verified mapping.
// pack_pts precomputes per-point A-frag halves (16B lo: k0-7, 16B hi: k8-15)
// and fp32 ||p||^2 into d_ws (2.25 MB). B-frags are rearranged in-register
// from the same pack at wave start.
// Floors: MFMA 262K*8cyc/CU = 3.4us; epilogue 8 v_min3/MFMA = 1.7us VALU.

#define NTOT 65536            // 2 sets * 8 batches * 4096 points
#define NPTS 4096

typedef __attribute__((ext_vector_type(8)))  short bf16x8;
typedef __attribute__((ext_vector_type(16))) float f32x16;

__device__ __forceinline__ unsigned short f2bf(float f) {
    union { float f; unsigned u; } v; v.f = f;
    return (unsigned short)((v.u + 0x7FFFu + ((v.u >> 16) & 1u)) >> 16);
}
__device__ __forceinline__ float bf2f(unsigned short h) {
    union { unsigned u; float f; } v; v.u = ((unsigned)h) << 16;
    return v.f;
}
__device__ __forceinline__ unsigned short m2(unsigned short h) {
    return f2bf(-2.0f * bf2f(h));     // exact: exponent+1, sign flip
}
__device__ __forceinline__ unsigned pack2(unsigned a, unsigned b) {
    return (a & 0xFFFFu) | (b << 16);
}

__global__ __launch_bounds__(256)
void pack_pts(const float* __restrict__ set1, const float* __restrict__ set2,
              uint4* __restrict__ lo, uint4* __restrict__ hi,
              float* __restrict__ q2o)
{
    const int i = blockIdx.x * 256 + threadIdx.x;     // 0..65535
    const float* __restrict__ src = (i < NTOT / 2) ? set1 : set2;
    const int idx = i & (NTOT / 2 - 1);
    const float x = src[3 * idx + 0];
    const float y = src[3 * idx + 1];
    const float z = src[3 * idx + 2];
    const unsigned short xh = f2bf(x), yh = f2bf(y), zh = f2bf(z);
    const unsigned short xl = f2bf(x - bf2f(xh));
    const unsigned short yl = f2bf(y - bf2f(yh));
    const unsigned short zl = f2bf(z - bf2f(zh));
    const float p2 = fmaf(x, x, fmaf(y, y, z * z));
    const unsigned short pa = f2bf(p2);
    const float r1 = p2 - bf2f(pa);
    const unsigned short pb = f2bf(r1);
    const unsigned short pc = f2bf(r1 - bf2f(pb));
    // A-frag lo half (k0-7):  [xh,yh,zh, xl,yl,zl, xh,yh]
    lo[i] = make_uint4(pack2(xh, yh), pack2(zh, xl), pack2(yl, zl), pack2(xh, yh));
    // A-frag hi half (k8-15): [zh, xl,yl,zl, pa,pb,pc, 0]
    hi[i] = make_uint4(pack2(zh, xl), pack2(yl, zl), pack2(pa, pb), pack2(pc, 0));
    q2o[i] = p2;
}

__device__ __forceinline__ float fold16(const f32x16 c, float m) {
    m = fminf(fminf(c[0],  c[1]),  m);
    m = fminf(fminf(c[2],  c[3]),  m);
    m = fminf(fminf(c[4],  c[5]),  m);
    m = fminf(fminf(c[6],  c[7]),  m);
    m = fminf(fminf(c[8],  c[9]),  m);
    m = fminf(fminf(c[10], c[11]), m);
    m = fminf(fminf(c[12], c[13]), m);
    m = fminf(fminf(c[14], c[15]), m);
    return m;
}

__global__ __launch_bounds__(512, 4)
void chamfer_main(const uint4* __restrict__ lo, const uint4* __restrict__ hi,
                  const float* __restrict__ q2arr, float* __restrict__ out)
{
    __shared__ float part[8][128];        // 4 KB

    const int blk = blockIdx.x;           // 0..511
    const int dir = blk >> 8;             // 0: q=set1 db=set2, 1: swapped
    const int rem = blk & 255;
    const int b   = rem >> 5;             // batch 0..7
    const int qc  = rem & 31;             // 128-query chunk 0..31

    const int qBase  = dir * (NTOT / 2) + b * NPTS + qc * 128;
    const int dbBase = (1 - dir) * (NTOT / 2) + b * NPTS;

    const int t    = threadIdx.x;
    const int lane = t & 63;
    const int w    = t >> 6;              // wave 0..7: point eighth
    const int col  = lane & 31;
    const int half = lane >> 5;           // k-half (0: k0-7, 1: k8-15)

    // ---- B-frags: 4 query tiles, rearranged from this lane's query A-pack ----
    const uint4* __restrict__ qsrc = half ? hi : lo;
    bf16x8 Bf[4];
    #pragma unroll
    for (int j = 0; j < 4; ++j) {
        const uint4 sv = qsrc[qBase + j * 32 + col];
        const unsigned short s0 = sv.x & 0xFFFF, s1 = sv.x >> 16;
        const unsigned short s2 = sv.y & 0xFFFF, s3 = sv.y >> 16;
        const unsigned short s4 = sv.z & 0xFFFF;
        uint4 bv;
        if (!half) {
            // [-2xh,-2yh,-2zh, -2xh,-2yh,-2zh, -2xl,-2yl]
            const unsigned short a0 = m2(s0), a1 = m2(s1), a2 = m2(s2);
            bv = make_uint4(pack2(a0, a1), pack2(a2, a0),
                            pack2(a1, a2), pack2(m2(s3), m2(s4)));
        } else {
            // hi slots: s0=zh s1=xl s2=yl s3=zl ...
            // [-2zl, -2xl,-2yl,-2zl, 1,1,1, 0]
            const unsigned short a3 = m2(s3);
            const unsigned one = 0x3F80u;
            bv = make_uint4(pack2(a3, m2(s1)), pack2(m2(s2), a3),
                            pack2(one, one), pack2(one, 0));
        }
        Bf[j] = *reinterpret_cast<bf16x8*>(&bv);
    }

    const f32x16 zero16 = {0,0,0,0,0,0,0,0,0,0,0,0,0,0,0,0};
    float dmin0 = FLT_MAX, dmin1 = FLT_MAX, dmin2 = FLT_MAX, dmin3 = FLT_MAX;

    // ---- scan this wave's 512 points: 16 tiles x (1 load + 4 MFMA + fold) ----
    const uint4* __restrict__ Abase = (half ? hi : lo) + (dbBase + w * 512 + col);

    #pragma unroll 4
    for (int pt = 0; pt < 16; ++pt) {
        const bf16x8 a = *reinterpret_cast<const bf16x8*>(Abase + pt * 32);
        f32x16 c;
        c = __builtin_amdgcn_mfma_f32_32x32x16_bf16(a, Bf[0], zero16, 0, 0, 0);
        dmin0 = fold16(c, dmin0);
        c = __builtin_amdgcn_mfma_f32_32x32x16_bf16(a, Bf[1], zero16, 0, 0, 0);
        dmin1 = fold16(c, dmin1);
        c = __builtin_amdgcn_mfma_f32_32x32x16_bf16(a, Bf[2], zero16, 0, 0, 0);
        dmin2 = fold16(c, dmin2);
        c = __builtin_amdgcn_mfma_f32_32x32x16_bf16(a, Bf[3], zero16, 0, 0, 0);
        dmin3 = fold16(c, dmin3);
    }

    // ---- combine row-halves (lane vs lane+32 hold disjoint point rows) ----
    float dmin[4] = {dmin0, dmin1, dmin2, dmin3};
    #pragma unroll
    for (int j = 0; j < 4; ++j) {
        const float v = fminf(dmin[j], __shfl_xor(dmin[j], 32));
        if (!half) part[w][j * 32 + col] = v;
    }
    __syncthreads();

    // ---- final: min over 8 wave-partials, add q^2, sqrt, sum-reduce ----
    float dist = 0.0f;
    if (t < 128) {
        float m = part[0][t];
        #pragma unroll
        for (int ww = 1; ww < 8; ++ww)
            m = fminf(m, part[ww][t]);
        const float q2 = q2arr[qBase + t];
        dist = sqrtf(fmaxf(q2 + m, 0.0f));
    }
    #pragma unroll
    for (int off = 32; off > 0; off >>= 1)
        dist += __shfl_down(dist, off);
    if (t < 128 && (t & 63) == 0)
        atomicAdd(out, dist * (1.0f / 134217728.0f));   // 1/(8*4096*4096)
}

extern "C" void kernel_launch(void* const* d_in, const int* in_sizes, int n_in,
                              void* d_out, int out_size, void* d_ws, size_t ws_size,
                              hipStream_t stream) {
    const float* s1 = (const float*)d_in[0];
    const float* s2 = (const float*)d_in[1];
    float* out = (float*)d_out;

    char* ws = (char*)d_ws;                         // needs 2.25 MB
    uint4* lo = (uint4*)ws;                         // [65536] x 16 B = 1 MB
    uint4* hi = (uint4*)(ws + (1u << 20));          // 1 MB
    float* q2 = (float*)(ws + (2u << 20));          // 256 KB

    hipMemsetAsync(out, 0, sizeof(float), stream);  // d_out poisoned 0xAA each call
    pack_pts<<<dim3(NTOT / 256), dim3(256), 0, stream>>>(s1, s2, lo, hi, q2);
    chamfer_main<<<dim3(512), dim3(512), 0, stream>>>(lo, hi, q2, out);
}